// Round 1
// 971.918 us; speedup vs baseline: 1.0306x; 1.0306x over previous
//
#include <hip/hip_runtime.h>

// ---------------------------------------------------------------------------
// Nystrom attention: split-bf16 (hi/lo, 3xMFMA) everywhere.
// R6: "split once, stream planes" — X/q/k/landmarks/OH are materialized as
// bf16 hi/lo planes at their producer; all hot GEMM staging becomes uint4
// copies (no per-tile split2 VALU). fp32 q/k/v/oh globals eliminated.
// XCD-swizzle on mfma_qkv / mfma_final.
// B=4, N=4096, DIM=512, H=8, DH=64, M=256, l=16, 6 pinv iters, conv K=33.
// ---------------------------------------------------------------------------

typedef __attribute__((ext_vector_type(8))) short bf16x8;
typedef __attribute__((ext_vector_type(4))) float f32x4;

constexpr size_t SP = 1048576;                 // one bf16 plane of [32][256][256] (float units)

// workspace layout (float units)
constexpr size_t O_XP  = 0;          // Xh/Xl planes; later zA,zB,Y2T; later oh fp32
constexpr size_t O_QP  = 8388608;    // q planes (hi/lo)
constexpr size_t O_KP  = 16777216;   // k planes; later pinv T-planes; later t2T; later OH planes
constexpr size_t O_VT  = 25165824;   // vT planes
constexpr size_t O_QL  = 33554432;   // qland fp32
constexpr size_t O_KL  = 34078720;   // kland fp32
constexpr size_t O_QLP = 34603008;   // qland planes
constexpr size_t O_KLP = 35127296;   // kland planes
constexpr size_t O_A2  = 35651584;   // attn2 fp32
constexpr size_t O_T1  = 37748736;
constexpr size_t O_RS3 = 38273024;
constexpr size_t O_SCAL= 38281216;
constexpr size_t O_T2  = 38281232;
constexpr size_t O_WQT = 38805520;
constexpr size_t O_WOT = 39591952;
constexpr size_t O_END = 39854096;   // ~159.4 MB

// ---------------------------------------------------------------------------
__device__ __forceinline__ void split2(float x, unsigned short& h,
                                       unsigned short& l) {
    unsigned u  = __float_as_uint(x);
    unsigned hb = (u + 0x7FFFu + ((u >> 16) & 1u)) & 0xFFFF0000u;  // RNE hi
    h = (unsigned short)(hb >> 16);
    float d = x - __uint_as_float(hb);
    l = (unsigned short)(__float_as_uint(d) >> 16);
}

__device__ __forceinline__ float b2f(unsigned short s) {
    return __uint_as_float((unsigned)s << 16);
}

__device__ __forceinline__ f32x4 mfma3(bf16x8 ah, bf16x8 al, bf16x8 bh,
                                       bf16x8 bl, f32x4 c) {
    c = __builtin_amdgcn_mfma_f32_16x16x32_bf16(ah, bh, c, 0, 0, 0);
    c = __builtin_amdgcn_mfma_f32_16x16x32_bf16(ah, bl, c, 0, 0, 0);
    c = __builtin_amdgcn_mfma_f32_16x16x32_bf16(al, bh, c, 0, 0, 0);
    return c;
}

// split a float4 into hi/lo planes, write packed uint2 at H[off], L[off]
__device__ __forceinline__ void stage_split4(float4 av, unsigned short* H,
                                             unsigned short* L, int off) {
    unsigned short h0, h1, h2, h3, l0, l1, l2, l3;
    split2(av.x, h0, l0); split2(av.y, h1, l1);
    split2(av.z, h2, l2); split2(av.w, h3, l3);
    uint2 ph, pl;
    ph.x = (unsigned)h0 | ((unsigned)h1 << 16);
    ph.y = (unsigned)h2 | ((unsigned)h3 << 16);
    pl.x = (unsigned)l0 | ((unsigned)l1 << 16);
    pl.y = (unsigned)l2 | ((unsigned)l3 << 16);
    *(uint2*)&H[off] = ph;
    *(uint2*)&L[off] = pl;
}

// ---------------------------------------------------------------------------
// X -> split planes (one-time)
// ---------------------------------------------------------------------------
__global__ void xsplit(const float* __restrict__ X,
                       unsigned short* __restrict__ Xh,
                       unsigned short* __restrict__ Xl) {
    int idx = blockIdx.x * 256 + threadIdx.x;
    float4 v = *(const float4*)(X + (size_t)idx * 4);
    stage_split4(v, Xh, Xl, idx * 4);
}

// ---------------------------------------------------------------------------
// pinv-family MFMA GEMM, 64x128 tile: C = alpha*(A@B) + beta*A_elem.
// A fp32 (split in-register); B = transposed bf16 planes BT[n][k].
// grid (N/128=2, M/64=4, 32), block 256.
// ---------------------------------------------------------------------------
template <int EPI, bool WF32, bool WT>
__global__ __launch_bounds__(256) void mfma_gemm(
    const float* __restrict__ A, int lda, long saA,
    const unsigned short* __restrict__ BTh,
    const unsigned short* __restrict__ BTl, int ldbt, long sbT,
    float* __restrict__ C, int ldc, long scC,
    unsigned short* __restrict__ CTh, unsigned short* __restrict__ CTl,
    int ldct, long sct, int K, float alpha, float beta) {
    __shared__ unsigned short Ah[64 * 40], Al[64 * 40];
    __shared__ unsigned short Bh[128 * 40], Bl[128 * 40];
    const int t = threadIdx.x;
    const int wave = t >> 6, lane = t & 63, lm = lane & 15, lq = lane >> 4;
    const int z = blockIdx.z;
    const int m0 = blockIdx.y * 64, n0 = blockIdx.x * 128;
    const float* Ab = A + (size_t)z * saA;
    const unsigned short* BhB = BTh + (size_t)z * sbT;
    const unsigned short* BlB = BTl + (size_t)z * sbT;

    f32x4 acc[8];
#pragma unroll
    for (int j = 0; j < 8; ++j) acc[j] = (f32x4){0.f, 0.f, 0.f, 0.f};

    for (int kt = 0; kt < K; kt += 32) {
#pragma unroll
        for (int r = 0; r < 2; ++r) {
            int id = t + r * 256, row = id >> 3, k4 = (id & 7) * 4;
            float4 av = *(const float4*)(Ab + (size_t)(m0 + row) * lda + kt + k4);
            stage_split4(av, Ah, Al, row * 40 + k4);
        }
#pragma unroll
        for (int r = 0; r < 2; ++r) {
            int id = t + r * 256, row = id >> 2, ko = (id & 3) * 8;
            *(uint4*)&Bh[row * 40 + ko] =
                *(const uint4*)(BhB + (size_t)(n0 + row) * ldbt + kt + ko);
            *(uint4*)&Bl[row * 40 + ko] =
                *(const uint4*)(BlB + (size_t)(n0 + row) * ldbt + kt + ko);
        }
        __syncthreads();
        bf16x8 ah = *(const bf16x8*)&Ah[(wave * 16 + lm) * 40 + lq * 8];
        bf16x8 al = *(const bf16x8*)&Al[(wave * 16 + lm) * 40 + lq * 8];
#pragma unroll
        for (int j = 0; j < 8; ++j) {
            bf16x8 bh = *(const bf16x8*)&Bh[(j * 16 + lm) * 40 + lq * 8];
            bf16x8 bl = *(const bf16x8*)&Bl[(j * 16 + lm) * 40 + lq * 8];
            acc[j] = mfma3(ah, al, bh, bl, acc[j]);
        }
        __syncthreads();
    }

    float* Cb = C + (size_t)z * scC;
    unsigned short* CThB = CTh + (size_t)z * sct;
    unsigned short* CTlB = CTl + (size_t)z * sct;
    const int r0 = m0 + wave * 16 + lq * 4;
#pragma unroll
    for (int j = 0; j < 8; ++j) {
        int c = n0 + j * 16 + lm;
        float vals[4] = {acc[j][0], acc[j][1], acc[j][2], acc[j][3]};
        if (EPI == 1) {
#pragma unroll
            for (int e = 0; e < 4; ++e)
                vals[e] = alpha * vals[e] + beta * Ab[(size_t)(r0 + e) * lda + c];
        }
        if (WF32) {
#pragma unroll
            for (int e = 0; e < 4; ++e)
                Cb[(size_t)(r0 + e) * ldc + c] = vals[e];
        }
        if (WT) {
            unsigned short hh[4], ll[4];
#pragma unroll
            for (int e = 0; e < 4; ++e) split2(vals[e], hh[e], ll[e]);
            uint2 ph, pl;
            ph.x = (unsigned)hh[0] | ((unsigned)hh[1] << 16);
            ph.y = (unsigned)hh[2] | ((unsigned)hh[3] << 16);
            pl.x = (unsigned)ll[0] | ((unsigned)ll[1] << 16);
            pl.y = (unsigned)ll[2] | ((unsigned)ll[3] << 16);
            *(uint2*)&CThB[(size_t)c * ldct + r0] = ph;
            *(uint2*)&CTlB[(size_t)c * ldct + r0] = pl;
        }
    }
}

// ---------------------------------------------------------------------------
// qkv MFMA GEMM: X planes [16384,512] @ w_qkv planes; emits q/k planes
// ([bh][n][d], q scaled 0.125) and vT planes [bh][dh][4096]. grid (12,128).
// ---------------------------------------------------------------------------
__global__ __launch_bounds__(256) void mfma_qkv(
    const unsigned short* __restrict__ Xh_, const unsigned short* __restrict__ Xl_,
    const unsigned short* __restrict__ WTh, const unsigned short* __restrict__ WTl,
    unsigned short* __restrict__ qh, unsigned short* __restrict__ ql,
    unsigned short* __restrict__ kh, unsigned short* __restrict__ kl,
    unsigned short* __restrict__ vTh, unsigned short* __restrict__ vTl) {
    __shared__ unsigned short Ah[128 * 40], Al[128 * 40];
    __shared__ unsigned short Bh[128 * 40], Bl[128 * 40];
    const int t = threadIdx.x;
    const int wave = t >> 6, lane = t & 63, lm = lane & 15, lq = lane >> 4;
    // XCD-aware bijective swizzle: nwg=1536, 1536/8=192 per XCD
    int orig = blockIdx.y * 12 + blockIdx.x;
    int wg = (orig & 7) * 192 + (orig >> 3);
    const int m0 = (wg / 12) * 128, n0 = (wg % 12) * 128;
    const int mb = (wave >> 1) * 64, nb = (wave & 1) * 64;
    f32x4 acc[4][4];
#pragma unroll
    for (int i = 0; i < 4; ++i)
#pragma unroll
        for (int j = 0; j < 4; ++j) acc[i][j] = (f32x4){0.f, 0.f, 0.f, 0.f};

    for (int kt = 0; kt < 512; kt += 32) {
#pragma unroll
        for (int r = 0; r < 2; ++r) {
            int id = t + r * 256, row = id >> 2, ko = (id & 3) * 8;
            *(uint4*)&Ah[row * 40 + ko] =
                *(const uint4*)(Xh_ + (size_t)(m0 + row) * 512 + kt + ko);
            *(uint4*)&Al[row * 40 + ko] =
                *(const uint4*)(Xl_ + (size_t)(m0 + row) * 512 + kt + ko);
        }
#pragma unroll
        for (int r = 0; r < 2; ++r) {
            int id = t + r * 256, row = id >> 2, ko = (id & 3) * 8;
            *(uint4*)&Bh[row * 40 + ko] =
                *(const uint4*)(WTh + (size_t)(n0 + row) * 512 + kt + ko);
            *(uint4*)&Bl[row * 40 + ko] =
                *(const uint4*)(WTl + (size_t)(n0 + row) * 512 + kt + ko);
        }
        __syncthreads();
        bf16x8 ah[4], al[4], bh[4], bl[4];
#pragma unroll
        for (int i = 0; i < 4; ++i) {
            ah[i] = *(const bf16x8*)&Ah[(mb + i * 16 + lm) * 40 + lq * 8];
            al[i] = *(const bf16x8*)&Al[(mb + i * 16 + lm) * 40 + lq * 8];
        }
#pragma unroll
        for (int j = 0; j < 4; ++j) {
            bh[j] = *(const bf16x8*)&Bh[(nb + j * 16 + lm) * 40 + lq * 8];
            bl[j] = *(const bf16x8*)&Bl[(nb + j * 16 + lm) * 40 + lq * 8];
        }
#pragma unroll
        for (int i = 0; i < 4; ++i)
#pragma unroll
            for (int j = 0; j < 4; ++j)
                acc[i][j] = mfma3(ah[i], al[i], bh[j], bl[j], acc[i][j]);
        __syncthreads();
    }
#pragma unroll
    for (int i = 0; i < 4; ++i)
#pragma unroll
        for (int j = 0; j < 4; ++j) {
            int r0 = m0 + mb + i * 16 + lq * 4;
            int c  = n0 + nb + j * 16 + lm;
            int which = c >> 9, h = (c >> 6) & 7, d = c & 63;
            int b = r0 >> 12, nbase = r0 & 4095;
            if (which == 2) {
                unsigned short hh[4], ll[4];
#pragma unroll
                for (int e = 0; e < 4; ++e) split2(acc[i][j][e], hh[e], ll[e]);
                uint2 ph, pl;
                ph.x = (unsigned)hh[0] | ((unsigned)hh[1] << 16);
                ph.y = (unsigned)hh[2] | ((unsigned)hh[3] << 16);
                pl.x = (unsigned)ll[0] | ((unsigned)ll[1] << 16);
                pl.y = (unsigned)ll[2] | ((unsigned)ll[3] << 16);
                size_t off = ((size_t)(b * 8 + h) * 64 + d) * 4096 + nbase;
                *(uint2*)&vTh[off] = ph;
                *(uint2*)&vTl[off] = pl;
            } else {
                unsigned short* Ph = which ? kh : qh;
                unsigned short* Pl = which ? kl : ql;
                float sc = which ? 1.0f : 0.125f;
#pragma unroll
                for (int e = 0; e < 4; ++e) {
                    unsigned short hh, ll;
                    split2(acc[i][j][e] * sc, hh, ll);
                    size_t off = (size_t)(b * 8 + h) * 262144 +
                                 (size_t)(nbase + e) * 64 + d;
                    Ph[off] = hh;
                    Pl[off] = ll;
                }
            }
        }
}

// ---------------------------------------------------------------------------
// final MFMA GEMM: out[16384,512] = OH planes (gathered) @ w_out planes.
// grid (4,128).
// ---------------------------------------------------------------------------
__global__ __launch_bounds__(256) void mfma_final(
    const unsigned short* __restrict__ OHh, const unsigned short* __restrict__ OHl,
    const unsigned short* __restrict__ WTh, const unsigned short* __restrict__ WTl,
    float* __restrict__ out) {
    __shared__ unsigned short Ah[128 * 40], Al[128 * 40];
    __shared__ unsigned short Bh[128 * 40], Bl[128 * 40];
    const int t = threadIdx.x;
    const int wave = t >> 6, lane = t & 63, lm = lane & 15, lq = lane >> 4;
    // XCD-aware bijective swizzle: nwg=512, 512/8=64 per XCD
    int orig = blockIdx.y * 4 + blockIdx.x;
    int wg = (orig & 7) * 64 + (orig >> 3);
    const int m0 = (wg >> 2) * 128, n0 = (wg & 3) * 128;
    const int mb = (wave >> 1) * 64, nb = (wave & 1) * 64;
    f32x4 acc[4][4];
#pragma unroll
    for (int i = 0; i < 4; ++i)
#pragma unroll
        for (int j = 0; j < 4; ++j) acc[i][j] = (f32x4){0.f, 0.f, 0.f, 0.f};

    for (int kt = 0; kt < 512; kt += 32) {
#pragma unroll
        for (int r = 0; r < 2; ++r) {
            int id = t + r * 256, row = id >> 2, ko = (id & 3) * 8;
            int gr = m0 + row, b = gr >> 12, n = gr & 4095;
            int kk = kt + ko;
            size_t off = (size_t)(b * 8 + (kk >> 6)) * 262144 +
                         (size_t)n * 64 + (kk & 63);
            *(uint4*)&Ah[row * 40 + ko] = *(const uint4*)(OHh + off);
            *(uint4*)&Al[row * 40 + ko] = *(const uint4*)(OHl + off);
        }
#pragma unroll
        for (int r = 0; r < 2; ++r) {
            int id = t + r * 256, row = id >> 2, ko = (id & 3) * 8;
            *(uint4*)&Bh[row * 40 + ko] =
                *(const uint4*)(WTh + (size_t)(n0 + row) * 512 + kt + ko);
            *(uint4*)&Bl[row * 40 + ko] =
                *(const uint4*)(WTl + (size_t)(n0 + row) * 512 + kt + ko);
        }
        __syncthreads();
        bf16x8 ah[4], al[4], bh[4], bl[4];
#pragma unroll
        for (int i = 0; i < 4; ++i) {
            ah[i] = *(const bf16x8*)&Ah[(mb + i * 16 + lm) * 40 + lq * 8];
            al[i] = *(const bf16x8*)&Al[(mb + i * 16 + lm) * 40 + lq * 8];
        }
#pragma unroll
        for (int j = 0; j < 4; ++j) {
            bh[j] = *(const bf16x8*)&Bh[(nb + j * 16 + lm) * 40 + lq * 8];
            bl[j] = *(const bf16x8*)&Bl[(nb + j * 16 + lm) * 40 + lq * 8];
        }
#pragma unroll
        for (int i = 0; i < 4; ++i)
#pragma unroll
            for (int j = 0; j < 4; ++j)
                acc[i][j] = mfma3(ah[i], al[i], bh[j], bl[j], acc[i][j]);
        __syncthreads();
    }
#pragma unroll
    for (int i = 0; i < 4; ++i)
#pragma unroll
        for (int j = 0; j < 4; ++j) {
            int r0 = m0 + mb + i * 16 + lq * 4;
            int c  = n0 + nb + j * 16 + lm;
#pragma unroll
            for (int e = 0; e < 4; ++e)
                out[(size_t)(r0 + e) * 512 + c] = acc[i][j][e];
        }
}

// ---------------------------------------------------------------------------
// F3 MFMA: t1 += exp(qland@k^T)@v, rs3 += rowsums. All operands pre-split
// planes (copy staging). grid (8, 4, 32).
// ---------------------------------------------------------------------------
__global__ __launch_bounds__(256) void attn3v_mfma(
    const unsigned short* __restrict__ qlh, const unsigned short* __restrict__ qll,
    const unsigned short* __restrict__ kh_, const unsigned short* __restrict__ kl_,
    const unsigned short* __restrict__ vTh, const unsigned short* __restrict__ vTl,
    float* __restrict__ t1, float* __restrict__ rs3) {
    __shared__ unsigned short Qh[4608], Ql[4608];
    __shared__ unsigned short Kh[4608], Kl[4608];
    __shared__ unsigned short Eh[4608], El[4608];
    const int t = threadIdx.x;
    const int wave = t >> 6, lane = t & 63, lm = lane & 15, lq = lane >> 4;
    const int bz = blockIdx.z, m0 = blockIdx.y * 64, c0 = blockIdx.x * 8;
    const unsigned short* qhb = qlh + (size_t)bz * 16384;
    const unsigned short* qlb = qll + (size_t)bz * 16384;
    const unsigned short* khb = kh_ + (size_t)bz * 262144;
    const unsigned short* klb = kl_ + (size_t)bz * 262144;
    const unsigned short* vhb = vTh + (size_t)bz * 262144;
    const unsigned short* vlb = vTl + (size_t)bz * 262144;
#pragma unroll
    for (int r = 0; r < 2; ++r) {
        int id = t + r * 256, row = id >> 3, ko = (id & 7) * 8;
        *(uint4*)&Qh[row * 72 + ko] =
            *(const uint4*)(qhb + (size_t)(m0 + row) * 64 + ko);
        *(uint4*)&Ql[row * 72 + ko] =
            *(const uint4*)(qlb + (size_t)(m0 + row) * 64 + ko);
    }
    f32x4 acc[4];
#pragma unroll
    for (int j = 0; j < 4; ++j) acc[j] = (f32x4){0.f, 0.f, 0.f, 0.f};
    float rsum[4] = {0.f, 0.f, 0.f, 0.f};
    __syncthreads();

    for (int c = c0; c < c0 + 8; ++c) {
        const int tok0 = c * 64;
#pragma unroll
        for (int r = 0; r < 2; ++r) {
            int id = t + r * 256, row = id >> 3, ko = (id & 7) * 8;
            *(uint4*)&Kh[row * 72 + ko] =
                *(const uint4*)(khb + (size_t)(tok0 + row) * 64 + ko);
            *(uint4*)&Kl[row * 72 + ko] =
                *(const uint4*)(klb + (size_t)(tok0 + row) * 64 + ko);
        }
        __syncthreads();
        bf16x8 a0  = *(const bf16x8*)&Qh[(wave * 16 + lm) * 72 + lq * 8];
        bf16x8 a0l = *(const bf16x8*)&Ql[(wave * 16 + lm) * 72 + lq * 8];
        bf16x8 a1  = *(const bf16x8*)&Qh[(wave * 16 + lm) * 72 + 32 + lq * 8];
        bf16x8 a1l = *(const bf16x8*)&Ql[(wave * 16 + lm) * 72 + 32 + lq * 8];
        f32x4 s[4];
#pragma unroll
        for (int j = 0; j < 4; ++j) s[j] = (f32x4){0.f, 0.f, 0.f, 0.f};
#pragma unroll
        for (int j = 0; j < 4; ++j) {
            bf16x8 b0  = *(const bf16x8*)&Kh[(j * 16 + lm) * 72 + lq * 8];
            bf16x8 b0l = *(const bf16x8*)&Kl[(j * 16 + lm) * 72 + lq * 8];
            bf16x8 b1  = *(const bf16x8*)&Kh[(j * 16 + lm) * 72 + 32 + lq * 8];
            bf16x8 b1l = *(const bf16x8*)&Kl[(j * 16 + lm) * 72 + 32 + lq * 8];
            s[j] = mfma3(a0, a0l, b0, b0l, s[j]);
            s[j] = mfma3(a1, a1l, b1, b1l, s[j]);
        }
        __syncthreads();
#pragma unroll
        for (int j = 0; j < 4; ++j)
#pragma unroll
            for (int e = 0; e < 4; ++e) {
                float ev = __expf(s[j][e]);
                rsum[e] += ev;
                unsigned short h, l;
                split2(ev, h, l);
                int off = (wave * 16 + lq * 4 + e) * 72 + j * 16 + lm;
                Eh[off] = h;
                El[off] = l;
            }
#pragma unroll
        for (int r = 0; r < 2; ++r) {
            int id = t + r * 256, dh = id >> 3, t8 = (id & 7) * 8;
            *(uint4*)&Kh[dh * 72 + t8] =
                *(const uint4*)(vhb + (size_t)dh * 4096 + tok0 + t8);
            *(uint4*)&Kl[dh * 72 + t8] =
                *(const uint4*)(vlb + (size_t)dh * 4096 + tok0 + t8);
        }
        __syncthreads();
        bf16x8 e0  = *(const bf16x8*)&Eh[(wave * 16 + lm) * 72 + lq * 8];
        bf16x8 e0l = *(const bf16x8*)&El[(wave * 16 + lm) * 72 + lq * 8];
        bf16x8 e1  = *(const bf16x8*)&Eh[(wave * 16 + lm) * 72 + 32 + lq * 8];
        bf16x8 e1l = *(const bf16x8*)&El[(wave * 16 + lm) * 72 + 32 + lq * 8];
#pragma unroll
        for (int j = 0; j < 4; ++j) {
            bf16x8 v0  = *(const bf16x8*)&Kh[(j * 16 + lm) * 72 + lq * 8];
            bf16x8 v0l = *(const bf16x8*)&Kl[(j * 16 + lm) * 72 + lq * 8];
            bf16x8 v1  = *(const bf16x8*)&Kh[(j * 16 + lm) * 72 + 32 + lq * 8];
            bf16x8 v1l = *(const bf16x8*)&Kl[(j * 16 + lm) * 72 + 32 + lq * 8];
            acc[j] = mfma3(e0, e0l, v0, v0l, acc[j]);
            acc[j] = mfma3(e1, e1l, v1, v1l, acc[j]);
        }
        __syncthreads();
    }
    float* t1b = t1 + (size_t)bz * 16384;
#pragma unroll
    for (int j = 0; j < 4; ++j)
#pragma unroll
        for (int e = 0; e < 4; ++e)
            atomicAdd(t1b + (size_t)(m0 + wave * 16 + lq * 4 + e) * 64 +
                          j * 16 + lm,
                      acc[j][e]);
#pragma unroll
    for (int e = 0; e < 4; ++e) {
        float vs = rsum[e];
        for (int mm = 1; mm < 16; mm <<= 1) vs += __shfl_xor(vs, mm);
        if (lm == 0)
            atomicAdd(rs3 + bz * 256 + m0 + wave * 16 + lq * 4 + e, vs);
    }
}

// ---------------------------------------------------------------------------
// F1 MFMA: oh = softmax(q@kland^T) @ t2 (normalized). q/kland from planes.
// grid (64, 32).
// ---------------------------------------------------------------------------
__global__ __launch_bounds__(256) void attn1t2_mfma(
    const unsigned short* __restrict__ qh_, const unsigned short* __restrict__ ql_,
    const unsigned short* __restrict__ klh, const unsigned short* __restrict__ kll,
    const unsigned short* __restrict__ t2Th,
    const unsigned short* __restrict__ t2Tl, float* __restrict__ oh) {
    __shared__ unsigned short Qh[4608], Ql[4608];
    __shared__ unsigned short Kh[4608], Kl[4608];
    __shared__ unsigned short Eh[4608], El[4608];
    const int t = threadIdx.x;
    const int wave = t >> 6, lane = t & 63, lm = lane & 15, lq = lane >> 4;
    const int bz = blockIdx.y, m0 = blockIdx.x * 64;
    const unsigned short* qhb = qh_ + (size_t)bz * 262144;
    const unsigned short* qlb = ql_ + (size_t)bz * 262144;
    const unsigned short* khb = klh + (size_t)bz * 16384;
    const unsigned short* klb = kll + (size_t)bz * 16384;
    const unsigned short* t2h = t2Th + (size_t)bz * 16384;
    const unsigned short* t2l = t2Tl + (size_t)bz * 16384;
#pragma unroll
    for (int r = 0; r < 2; ++r) {
        int id = t + r * 256, row = id >> 3, ko = (id & 7) * 8;
        *(uint4*)&Qh[row * 72 + ko] =
            *(const uint4*)(qhb + (size_t)(m0 + row) * 64 + ko);
        *(uint4*)&Ql[row * 72 + ko] =
            *(const uint4*)(qlb + (size_t)(m0 + row) * 64 + ko);
    }
    f32x4 acc[4];
#pragma unroll
    for (int j = 0; j < 4; ++j) acc[j] = (f32x4){0.f, 0.f, 0.f, 0.f};
    float rsum[4] = {0.f, 0.f, 0.f, 0.f};
    __syncthreads();

    for (int lc = 0; lc < 4; ++lc) {
        const int l0 = lc * 64;
#pragma unroll
        for (int r = 0; r < 2; ++r) {
            int id = t + r * 256, row = id >> 3, ko = (id & 7) * 8;
            *(uint4*)&Kh[row * 72 + ko] =
                *(const uint4*)(khb + (size_t)(l0 + row) * 64 + ko);
            *(uint4*)&Kl[row * 72 + ko] =
                *(const uint4*)(klb + (size_t)(l0 + row) * 64 + ko);
        }
        __syncthreads();
        bf16x8 a0  = *(const bf16x8*)&Qh[(wave * 16 + lm) * 72 + lq * 8];
        bf16x8 a0l = *(const bf16x8*)&Ql[(wave * 16 + lm) * 72 + lq * 8];
        bf16x8 a1  = *(const bf16x8*)&Qh[(wave * 16 + lm) * 72 + 32 + lq * 8];
        bf16x8 a1l = *(const bf16x8*)&Ql[(wave * 16 + lm) * 72 + 32 + lq * 8];
        f32x4 s[4];
#pragma unroll
        for (int j = 0; j < 4; ++j) s[j] = (f32x4){0.f, 0.f, 0.f, 0.f};
#pragma unroll
        for (int j = 0; j < 4; ++j) {
            bf16x8 b0  = *(const bf16x8*)&Kh[(j * 16 + lm) * 72 + lq * 8];
            bf16x8 b0l = *(const bf16x8*)&Kl[(j * 16 + lm) * 72 + lq * 8];
            bf16x8 b1  = *(const bf16x8*)&Kh[(j * 16 + lm) * 72 + 32 + lq * 8];
            bf16x8 b1l = *(const bf16x8*)&Kl[(j * 16 + lm) * 72 + 32 + lq * 8];
            s[j] = mfma3(a0, a0l, b0, b0l, s[j]);
            s[j] = mfma3(a1, a1l, b1, b1l, s[j]);
        }
        __syncthreads();
#pragma unroll
        for (int j = 0; j < 4; ++j)
#pragma unroll
            for (int e = 0; e < 4; ++e) {
                float ev = __expf(s[j][e]);
                rsum[e] += ev;
                unsigned short h, l;
                split2(ev, h, l);
                int off = (wave * 16 + lq * 4 + e) * 72 + j * 16 + lm;
                Eh[off] = h;
                El[off] = l;
            }
#pragma unroll
        for (int r = 0; r < 2; ++r) {
            int id = t + r * 256, dh = id >> 3, t8 = (id & 7) * 8;
            *(uint4*)&Kh[dh * 72 + t8] =
                *(const uint4*)(t2h + (size_t)dh * 256 + l0 + t8);
            *(uint4*)&Kl[dh * 72 + t8] =
                *(const uint4*)(t2l + (size_t)dh * 256 + l0 + t8);
        }
        __syncthreads();
        bf16x8 e0  = *(const bf16x8*)&Eh[(wave * 16 + lm) * 72 + lq * 8];
        bf16x8 e0l = *(const bf16x8*)&El[(wave * 16 + lm) * 72 + lq * 8];
        bf16x8 e1  = *(const bf16x8*)&Eh[(wave * 16 + lm) * 72 + 32 + lq * 8];
        bf16x8 e1l = *(const bf16x8*)&El[(wave * 16 + lm) * 72 + 32 + lq * 8];
#pragma unroll
        for (int j = 0; j < 4; ++j) {
            bf16x8 v0  = *(const bf16x8*)&Kh[(j * 16 + lm) * 72 + lq * 8];
            bf16x8 v0l = *(const bf16x8*)&Kl[(j * 16 + lm) * 72 + lq * 8];
            bf16x8 v1  = *(const bf16x8*)&Kh[(j * 16 + lm) * 72 + 32 + lq * 8];
            bf16x8 v1l = *(const bf16x8*)&Kl[(j * 16 + lm) * 72 + 32 + lq * 8];
            acc[j] = mfma3(e0, e0l, v0, v0l, acc[j]);
            acc[j] = mfma3(e1, e1l, v1, v1l, acc[j]);
        }
        __syncthreads();
    }
    float rinv[4];
#pragma unroll
    for (int e = 0; e < 4; ++e) {
        float vs = rsum[e];
        for (int mm = 1; mm < 16; mm <<= 1) vs += __shfl_xor(vs, mm);
        rinv[e] = 1.0f / vs;
    }
    float* ohb = oh + (size_t)bz * 262144;
#pragma unroll
    for (int j = 0; j < 4; ++j)
#pragma unroll
        for (int e = 0; e < 4; ++e)
            ohb[(size_t)(m0 + wave * 16 + lq * 4 + e) * 64 + j * 16 + lm] =
                acc[j][e] * rinv[e];
}

// ---------------------------------------------------------------------------
// weight transpose+split: W[512][N] -> planes T[N][512]
// ---------------------------------------------------------------------------
__global__ void wtrans(const float* __restrict__ W, int N,
                       unsigned short* __restrict__ Th,
                       unsigned short* __restrict__ Tl) {
    int idx = blockIdx.x * 256 + threadIdx.x;
    int n = idx >> 9, kk = idx & 511;
    float x = W[(size_t)kk * N + n];
    unsigned short h, l;
    split2(x, h, l);
    Th[idx] = h;
    Tl[idx] = l;
}

// ---------------------------------------------------------------------------
// fp32 64x64 micro-kernel + gemm_bk (attn2 + t2 only)
// ---------------------------------------------------------------------------
__device__ __forceinline__ void mt16(const float* As, const float* Bs,
                                     int ty4, int tx4, float (&acc)[4][4]) {
#pragma unroll
    for (int kk = 0; kk < 16; ++kk) {
        float4 a4 = *(const float4*)(As + kk * 68 + ty4);
        float4 b4 = *(const float4*)(Bs + kk * 68 + tx4);
        float aa[4] = {a4.x, a4.y, a4.z, a4.w};
        float bb[4] = {b4.x, b4.y, b4.z, b4.w};
#pragma unroll
        for (int u = 0; u < 4; ++u)
#pragma unroll
            for (int w = 0; w < 4; ++w)
                acc[u][w] += aa[u] * bb[w];
    }
}

template <bool TRANSB, bool DIVB, bool WTOUT>
__global__ __launch_bounds__(256) void gemm_bk(
    const float* __restrict__ A, int saA, int lda,
    const float* __restrict__ B, int sbB, int ldb,
    float* __restrict__ C, int scC, int ldc,
    int K, const float* __restrict__ divv,
    unsigned short* __restrict__ CTh, unsigned short* __restrict__ CTl) {
    __shared__ float As[16 * 68];
    __shared__ float Bs[16 * 68];
    const int t  = threadIdx.x;
    const int z  = blockIdx.z;
    const int m0 = blockIdx.y * 64;
    const int n0 = blockIdx.x * 64;
    const float* Ab = A + (size_t)z * saA;
    const float* Bb = B + (size_t)z * sbB;
    float*       Cb = C + (size_t)z * scC;
    const int tx4 = (t & 15) * 4;
    const int ty4 = (t >> 4) * 4;
    const int ar  = t >> 2, ak = (t & 3) * 4;
    const int bkr = t >> 4, bc4 = (t & 15) * 4;
    float acc[4][4] = {};
    for (int kt = 0; kt < K; kt += 16) {
        float4 av = *(const float4*)(Ab + (size_t)(m0 + ar) * lda + kt + ak);
        float4 bv;
        if (TRANSB) {
            bv = *(const float4*)(Bb + (size_t)(n0 + ar) * ldb + kt + ak);
        } else {
            bv = *(const float4*)(Bb + (size_t)(kt + bkr) * ldb + n0 + bc4);
            if (DIVB) {
                float r = 1.0f / divv[z * K + kt + bkr];
                bv.x *= r; bv.y *= r; bv.z *= r; bv.w *= r;
            }
        }
        As[(ak + 0) * 68 + ar] = av.x;
        As[(ak + 1) * 68 + ar] = av.y;
        As[(ak + 2) * 68 + ar] = av.z;
        As[(ak + 3) * 68 + ar] = av.w;
        if (TRANSB) {
            Bs[(ak + 0) * 68 + ar] = bv.x;
            Bs[(ak + 1) * 68 + ar] = bv.y;
            Bs[(ak + 2) * 68 + ar] = bv.z;
            Bs[(ak + 3) * 68 + ar] = bv.w;
        } else {
            *(float4*)(Bs + bkr * 68 + bc4) = bv;
        }
        __syncthreads();
        mt16(As, Bs, ty4, tx4, acc);
        __syncthreads();
    }
#pragma unroll
    for (int u = 0; u < 4; ++u) {
        int row = m0 + ty4 + u;
        *(float4*)(Cb + (size_t)row * ldc + n0 + tx4) =
            make_float4(acc[u][0], acc[u][1], acc[u][2], acc[u][3]);
    }
    if (WTOUT) {
#pragma unroll
        for (int w = 0; w < 4; ++w) {
            unsigned short hh[4], ll[4];
#pragma unroll
            for (int u = 0; u < 4; ++u) split2(acc[u][w], hh[u], ll[u]);
            uint2 ph, pl;
            ph.x = (unsigned)hh[0] | ((unsigned)hh[1] << 16);
            ph.y = (unsigned)hh[2] | ((unsigned)hh[3] << 16);
            pl.x = (unsigned)ll[0] | ((unsigned)ll[1] << 16);
            pl.y = (unsigned)ll[2] | ((unsigned)ll[3] << 16);
            size_t off = (size_t)z * 16384 + (size_t)(n0 + tx4 + w) * 256 +
                         m0 + ty4;
            *(uint2*)&CTh[off] = ph;
            *(uint2*)&CTl[off] = pl;
        }
    }
}

// ---------------------------------------------------------------------------
// small kernels
// ---------------------------------------------------------------------------
__global__ void zero_f(float* __restrict__ p, int n) {
    int i = blockIdx.x * 256 + threadIdx.x;
    if (i < n) p[i] = 0.f;
}

// landmark mean from split planes; emits fp32 + split planes
__global__ void landmark_mean_p(const unsigned short* __restrict__ sh,
                                const unsigned short* __restrict__ sl,
                                float* __restrict__ dst,
                                unsigned short* __restrict__ dh,
                                unsigned short* __restrict__ dl) {
    int o = blockIdx.x * 256 + threadIdx.x;
    int d = o & 63, m = (o >> 6) & 255, bh = o >> 14;
    size_t base = (size_t)bh * 262144 + (size_t)m * 1024 + d;
    float acc = 0.f;
#pragma unroll
    for (int j = 0; j < 16; ++j)
        acc += b2f(sh[base + j * 64]) + b2f(sl[base + j * 64]);
    float v = acc * (1.0f / 16.0f);
    dst[o] = v;
    unsigned short h, l;
    split2(v, h, l);
    dh[o] = h;
    dl[o] = l;
}

__global__ void softmax_rows(float* __restrict__ a) {
    __shared__ float red[256];
    int row = blockIdx.x, t = threadIdx.x;
    float v = a[(size_t)row * 256 + t];
    red[t] = v;
    __syncthreads();
    for (int s = 128; s > 0; s >>= 1) {
        if (t < s) red[t] = fmaxf(red[t], red[t + s]);
        __syncthreads();
    }
    float mx = red[0];
    __syncthreads();
    float e = __expf(v - mx);
    red[t] = e;
    __syncthreads();
    for (int s = 128; s > 0; s >>= 1) {
        if (t < s) red[t] += red[t + s];
        __syncthreads();
    }
    a[(size_t)row * 256 + t] = e / red[0];
}

__global__ __launch_bounds__(256) void scalar_prep(const float* __restrict__ a,
                                                   float* __restrict__ scal) {
    __shared__ float red[256];
    int bh = blockIdx.x, t = threadIdx.x;
    const float* ab = a + (size_t)bh * 65536;
    float cs = 0.f;
    for (int i = 0; i < 256; ++i) cs += ab[i * 256 + t];
    red[t] = cs;
    __syncthreads();
    for (int s = 128; s > 0; s >>= 1) {
        if (t < s) red[t] = fmaxf(red[t], red[t + s]);
        __syncthreads();
    }
    float mcol = red[0];
    __syncthreads();
    float rs = 0.f;
    for (int j = 0; j < 256; ++j) rs += ab[t * 256 + j];
    red[t] = rs;
    __syncthreads();
    for (int s = 128; s > 0; s >>= 1) {
        if (t < s) red[t] = fmaxf(red[t], red[t + s]);
        __syncthreads();
    }
    if (t == 0) {
        atomicMax((unsigned int*)&scal[0], __float_as_uint(mcol));
        atomicMax((unsigned int*)&scal[1], __float_as_uint(red[0]));
    }
}

__global__ void zinit(const float* __restrict__ a, float* __restrict__ zz,
                      unsigned short* __restrict__ zTh,
                      unsigned short* __restrict__ zTl,
                      const float* __restrict__ scal) {
    int idx = blockIdx.x * 256 + threadIdx.x;
    int bh = idx >> 16, r = (idx >> 8) & 255, c = idx & 255;
    float denom = scal[0] * scal[1] + 1e-8f;
    float v = a[idx] / denom;
    zz[((size_t)bh << 16) + ((size_t)c << 8) + r] = v;
    unsigned short h, l;
    split2(v, h, l);
    zTh[idx] = h;
    zTl[idx] = l;
}

// ---------------------------------------------------------------------------
// LDS-tiled depthwise conv reading vT planes; emits OH planes (oh + conv).
// grid (32 tiles, 32 bh). Each block: 128 tokens x 64 dh; 160-token window.
// ---------------------------------------------------------------------------
__global__ __launch_bounds__(256) void conv_tiled(
    const float* __restrict__ ohin, const unsigned short* __restrict__ vTh,
    const unsigned short* __restrict__ vTl, const float* __restrict__ wres,
    unsigned short* __restrict__ OHh, unsigned short* __restrict__ OHl) {
    __shared__ float Vs[160 * 65];
    __shared__ float Ws[33];
    const int t = threadIdx.x;
    const int bh = blockIdx.y;
    const int n0 = blockIdx.x * 128;
    const int h = bh & 7;
    if (t < 33) Ws[t] = wres[h * 33 + t];
    const unsigned short* vhb = vTh + (size_t)bh * 262144;
    const unsigned short* vlb = vTl + (size_t)bh * 262144;
#pragma unroll
    for (int r = 0; r < 5; ++r) {
        int id = t + r * 256;               // 0..1279: 64 dh x 20 chunks of 8
        int d = id / 20, ch = id - d * 20;
        int n = n0 - 16 + ch * 8;
        uint4 h4 = make_uint4(0u, 0u, 0u, 0u);
        uint4 l4 = make_uint4(0u, 0u, 0u, 0u);
        if ((unsigned)n < 4096u) {
            h4 = *(const uint4*)(vhb + (size_t)d * 4096 + n);
            l4 = *(const uint4*)(vlb + (size_t)d * 4096 + n);
        }
        const unsigned short* hp = (const unsigned short*)&h4;
        const unsigned short* lp = (const unsigned short*)&l4;
        int row0 = ch * 8;
#pragma unroll
        for (int i = 0; i < 8; ++i)
            Vs[(row0 + i) * 65 + d] = b2f(hp[i]) + b2f(lp[i]);
    }
    __syncthreads();
    const int d = t & 63;
    const int g0 = (t >> 6) * 32;
    const float* ohb = ohin + (size_t)bh * 262144 + (size_t)n0 * 64;
    unsigned short* Hh = OHh + (size_t)bh * 262144 + (size_t)n0 * 64;
    unsigned short* Hl = OHl + (size_t)bh * 262144 + (size_t)n0 * 64;
    float w[33];
#pragma unroll
    for (int j = 0; j < 33; ++j) w[j] = Vs[(g0 + j) * 65 + d];
#pragma unroll
    for (int i = 0; i < 32; ++i) {
        float acc = ohb[(size_t)(g0 + i) * 64 + d];
#pragma unroll
        for (int tt = 0; tt < 33; ++tt) acc += w[tt] * Ws[tt];
        unsigned short hh, ll;
        split2(acc, hh, ll);
        Hh[(size_t)(g0 + i) * 64 + d] = hh;
        Hl[(size_t)(g0 + i) * 64 + d] = ll;
        if (i < 31) {
#pragma unroll
            for (int j = 0; j < 32; ++j) w[j] = w[j + 1];
            w[32] = Vs[(g0 + i + 33) * 65 + d];
        }
    }
}

// ---------------------------------------------------------------------------
extern "C" void kernel_launch(void* const* d_in, const int* in_sizes, int n_in,
                              void* d_out, int out_size, void* d_ws, size_t ws_size,
                              hipStream_t stream) {
    const float* x     = (const float*)d_in[0];
    const float* w_qkv = (const float*)d_in[1];
    const float* w_out = (const float*)d_in[2];
    const float* w_res = (const float*)d_in[3];
    float* out = (float*)d_out;
    float* ws  = (float*)d_ws;

    // planes (ushort units)
    unsigned short* Xh  = (unsigned short*)(ws + O_XP);
    unsigned short* Xl  = Xh + 8388608;
    unsigned short* qh  = (unsigned short*)(ws + O_QP);
    unsigned short* ql  = qh + 8388608;
    unsigned short* kh  = (unsigned short*)(ws + O_KP);
    unsigned short* kl  = kh + 8388608;
    unsigned short* vTh = (unsigned short*)(ws + O_VT);
    unsigned short* vTl = vTh + 8388608;
    unsigned short* qlh = (unsigned short*)(ws + O_QLP);
    unsigned short* qll = qlh + 524288;
    unsigned short* klh = (unsigned short*)(ws + O_KLP);
    unsigned short* kll = klh + 524288;

    float* qland = ws + O_QL;
    float* kland = ws + O_KL;
    float* attn2 = ws + O_A2;
    float* t1    = ws + O_T1;
    float* rs3   = ws + O_RS3;
    float* scal  = ws + O_SCAL;
    float* t2    = ws + O_T2;

    // pinv-phase aliases (k planes region is dead after attn3v)
    unsigned short* PB   = (unsigned short*)(ws + O_KP);
    unsigned short* ZT0h = PB;
    unsigned short* ZT0l = PB + 2097152;
    unsigned short* ZT1h = PB + 4194304;
    unsigned short* ZT1l = PB + 6291456;
    unsigned short* XZTh = PB + 8388608;
    unsigned short* XZTl = PB + 10485760;
    unsigned short* Y1Th = PB + 12582912;
    unsigned short* Y1Tl = PB + 14680064;
    // X-plane region is dead after qkv: hosts zA/zB + Y2T, later oh fp32
    float* zA = ws + O_XP;
    float* zB = zA + 2097152;
    unsigned short* Y2Th = (unsigned short*)(ws + O_XP + 4194304);
    unsigned short* Y2Tl = Y2Th + 2097152;
    // post-pinv aliases
    unsigned short* t2Th = PB;            // pinv planes dead
    unsigned short* t2Tl = PB + 524288;
    float* ohf = ws + O_XP;               // zA/zB/Y2T dead
    unsigned short* OHh = PB;             // t2T dead after attn1t2
    unsigned short* OHl = PB + 8388608;

    unsigned short* WQTh = (unsigned short*)(ws + O_WQT);
    unsigned short* WQTl = WQTh + 786432;
    unsigned short* WOTh = (unsigned short*)(ws + O_WOT);
    unsigned short* WOTl = WOTh + 262144;

    zero_f<<<2081, 256, 0, stream>>>(t1, 532496);   // t1+rs3+scal
    wtrans<<<3072, 256, 0, stream>>>(w_qkv, 1536, WQTh, WQTl);
    wtrans<<<1024, 256, 0, stream>>>(w_out, 512, WOTh, WOTl);
    xsplit<<<8192, 256, 0, stream>>>(x, Xh, Xl);

    mfma_qkv<<<dim3(12, 128), 256, 0, stream>>>(Xh, Xl, WQTh, WQTl,
                                                qh, ql, kh, kl, vTh, vTl);

    landmark_mean_p<<<2048, 256, 0, stream>>>(qh, ql, qland, qlh, qll);
    landmark_mean_p<<<2048, 256, 0, stream>>>(kh, kl, kland, klh, kll);

    gemm_bk<true, false, false><<<dim3(4, 4, 32), 256, 0, stream>>>(
        qland, 16384, 64, kland, 16384, 64, attn2, 65536, 256, 64, nullptr,
        nullptr, nullptr);
    softmax_rows<<<8192, 256, 0, stream>>>(attn2);
    scalar_prep<<<32, 256, 0, stream>>>(attn2, scal);

    // F3 before pinv (k and vT planes consumed here; k planes die here)
    attn3v_mfma<<<dim3(8, 4, 32), 256, 0, stream>>>(qlh, qll, kh, kl,
                                                    vTh, vTl, t1, rs3);

    zinit<<<8192, 256, 0, stream>>>(attn2, zA, ZT0h, ZT0l, scal);

    unsigned short* ZTh[2] = {ZT0h, ZT1h};
    unsigned short* ZTl[2] = {ZT0l, ZT1l};
    float* Zf[2] = {zA, zB};
    int cur = 0;
    const dim3 pg(2, 4, 32);
    for (int it = 0; it < 6; ++it) {
        float* zc  = Zf[cur];
        float* xzf = Zf[1 - cur];
        mfma_gemm<0, true, true><<<pg, 256, 0, stream>>>(
            attn2, 256, 65536, ZTh[cur], ZTl[cur], 256, 65536,
            xzf, 256, 65536, XZTh, XZTl, 256, 65536, 256, 0.f, 0.f);
        mfma_gemm<1, false, true><<<pg, 256, 0, stream>>>(
            xzf, 256, 65536, XZTh, XZTl, 256, 65536,
            nullptr, 256, 65536, Y1Th, Y1Tl, 256, 65536, 256, -1.f, 7.f);
        mfma_gemm<1, false, true><<<pg, 256, 0, stream>>>(
            xzf, 256, 65536, Y1Th, Y1Tl, 256, 65536,
            nullptr, 256, 65536, Y2Th, Y2Tl, 256, 65536, 256, -1.f, 15.f);
        mfma_gemm<1, true, true><<<pg, 256, 0, stream>>>(
            zc, 256, 65536, Y2Th, Y2Tl, 256, 65536,
            xzf, 256, 65536, ZTh[1 - cur], ZTl[1 - cur], 256, 65536,
            256, -0.25f, 3.25f);
        cur = 1 - cur;
    }
    float* zfin = Zf[cur];

    // t2 = z @ (t1 / rs3); also emit t2^T split planes (into dead ZT0 region)
    gemm_bk<false, true, true><<<dim3(1, 4, 32), 256, 0, stream>>>(
        zfin, 65536, 256, t1, 16384, 64, t2, 16384, 64, 256, rs3,
        t2Th, t2Tl);

    // F1: oh = softmax(q@kland^T)@t2 -> ohf (X-plane region, now dead)
    attn1t2_mfma<<<dim3(64, 32), 256, 0, stream>>>(qh, ql, klh, kll,
                                                   t2Th, t2Tl, ohf);

    // OH planes = oh + depthwise conv(v), from vT planes
    conv_tiled<<<dim3(32, 32), 256, 0, stream>>>(ohf, vTh, vTl, w_res,
                                                 OHh, OHl);

    mfma_final<<<dim3(4, 128), 256, 0, stream>>>(OHh, OHl, WOTh, WOTl, out);

    (void)in_sizes; (void)n_in; (void)out_size; (void)ws_size;
}